// Round 3
// baseline (27317.169 us; speedup 1.0000x reference)
//
#include <hip/hip_runtime.h>
#include <hip/hip_bf16.h>
#include <math.h>

#define T_TOK 2048
#define HIDDEN 512
#define FFDIM 2048
#define VOCAB 50257

// ---------------- embedding gather (f32 -> f32) ----------------
__global__ __launch_bounds__(256) void gather_rows(const int* __restrict__ tokens,
                                                   const float* __restrict__ embed,
                                                   float* __restrict__ h) {
    int t = blockIdx.x;
    int tok = tokens[t];
    const float2* src = (const float2*)(embed + (size_t)tok * HIDDEN);
    float2* dst = (float2*)(h + (size_t)t * HIDDEN);
    dst[threadIdx.x] = src[threadIdx.x];
}

// ---------------- LayerNorm (one block per row of 512) ----------------
__global__ __launch_bounds__(256) void ln_rows(const float* __restrict__ x,
                                               const float* __restrict__ g,
                                               const float* __restrict__ b,
                                               float* __restrict__ y) {
    int t = blockIdx.x;
    int tid = threadIdx.x;
    const float* xr = x + (size_t)t * HIDDEN;
    float v0 = xr[tid], v1 = xr[tid + 256];
    float s = v0 + v1;
    float q = v0 * v0 + v1 * v1;
    for (int off = 32; off > 0; off >>= 1) {
        s += __shfl_down(s, off);
        q += __shfl_down(q, off);
    }
    __shared__ float ss[4], qq[4];
    int w = tid >> 6;
    if ((tid & 63) == 0) { ss[w] = s; qq[w] = q; }
    __syncthreads();
    float S = ss[0] + ss[1] + ss[2] + ss[3];
    float Q = qq[0] + qq[1] + qq[2] + qq[3];
    float mu = S * (1.0f / HIDDEN);
    float var = Q * (1.0f / HIDDEN) - mu * mu;
    float r = rsqrtf(var + 1e-5f);
    float* yr = y + (size_t)t * HIDDEN;
    yr[tid]       = (v0 - mu) * r * g[tid]       + b[tid];
    yr[tid + 256] = (v1 - mu) * r * g[tid + 256] + b[tid + 256];
}

// ---------------- f32 GEMM: C[M,N] = A[M,K](rm) x B[K,N](rm) ----------------
// 64x64 tile, 256 threads, 4x4 micro-tile. ACT=1 -> exact GELU. HASBIAS -> +bias.
template <int ACT, int HASBIAS>
__global__ __launch_bounds__(256) void gemm_rrr(const float* __restrict__ A,
                                                const float* __restrict__ B,
                                                const float* __restrict__ bias,
                                                float* __restrict__ C,
                                                int M, int N, int K) {
    __shared__ float As[16][64];
    __shared__ float Bs[16][64];
    int tid = threadIdx.x;
    int row0 = blockIdx.y * 64, col0 = blockIdx.x * 64;
    int tx = tid & 15, ty = tid >> 4;
    int ar = tid >> 2, ak = (tid & 3) << 2;      // A: row ar, 4 k's starting ak
    int bk = tid >> 4, bc = (tid & 15) << 2;     // B: k row bk, 4 cols starting bc
    float acc[4][4] = {{0.f}};
    for (int k0 = 0; k0 < K; k0 += 16) {
        float4 av = *(const float4*)(A + (size_t)(row0 + ar) * K + k0 + ak);
        As[ak + 0][ar] = av.x; As[ak + 1][ar] = av.y;
        As[ak + 2][ar] = av.z; As[ak + 3][ar] = av.w;
        float4 bv = *(const float4*)(B + (size_t)(k0 + bk) * N + col0 + bc);
        Bs[bk][bc + 0] = bv.x; Bs[bk][bc + 1] = bv.y;
        Bs[bk][bc + 2] = bv.z; Bs[bk][bc + 3] = bv.w;
        __syncthreads();
#pragma unroll
        for (int k = 0; k < 16; ++k) {
            float a0 = As[k][ty * 4 + 0], a1 = As[k][ty * 4 + 1];
            float a2 = As[k][ty * 4 + 2], a3 = As[k][ty * 4 + 3];
            float b0 = Bs[k][tx * 4 + 0], b1 = Bs[k][tx * 4 + 1];
            float b2 = Bs[k][tx * 4 + 2], b3 = Bs[k][tx * 4 + 3];
            acc[0][0] += a0 * b0; acc[0][1] += a0 * b1; acc[0][2] += a0 * b2; acc[0][3] += a0 * b3;
            acc[1][0] += a1 * b0; acc[1][1] += a1 * b1; acc[1][2] += a1 * b2; acc[1][3] += a1 * b3;
            acc[2][0] += a2 * b0; acc[2][1] += a2 * b1; acc[2][2] += a2 * b2; acc[2][3] += a2 * b3;
            acc[3][0] += a3 * b0; acc[3][1] += a3 * b1; acc[3][2] += a3 * b2; acc[3][3] += a3 * b3;
        }
        __syncthreads();
    }
#pragma unroll
    for (int i = 0; i < 4; ++i) {
        int r = row0 + ty * 4 + i;
#pragma unroll
        for (int j = 0; j < 4; ++j) {
            int c = col0 + tx * 4 + j;
            float v = acc[i][j];
            if (HASBIAS) v += bias[c];
            if (ACT) v = 0.5f * v * (1.0f + erff(v * 0.70710678118654752f));
            C[(size_t)r * N + c] = v;
        }
    }
}

// ---------------- head GEMM: C[M,N] = A[M,K](rm) x B[N,K](rm)^T ----------------
__global__ __launch_bounds__(256) void gemm_head(const float* __restrict__ A,
                                                 const float* __restrict__ Bm,
                                                 float* __restrict__ C,
                                                 int M, int N, int K) {
    __shared__ float As[16][64];
    __shared__ float Bs[16][64];
    int tid = threadIdx.x;
    int row0 = blockIdx.y * 64, col0 = blockIdx.x * 64;
    int tx = tid & 15, ty = tid >> 4;
    int ar = tid >> 2, ak = (tid & 3) << 2;
    float acc[4][4] = {{0.f}};
    for (int k0 = 0; k0 < K; k0 += 16) {
        float4 av = *(const float4*)(A + (size_t)(row0 + ar) * K + k0 + ak);
        As[ak + 0][ar] = av.x; As[ak + 1][ar] = av.y;
        As[ak + 2][ar] = av.z; As[ak + 3][ar] = av.w;
        int bn = col0 + ar;
        if (bn < N) {
            float4 bv = *(const float4*)(Bm + (size_t)bn * K + k0 + ak);
            Bs[ak + 0][ar] = bv.x; Bs[ak + 1][ar] = bv.y;
            Bs[ak + 2][ar] = bv.z; Bs[ak + 3][ar] = bv.w;
        } else {
            Bs[ak + 0][ar] = 0.f; Bs[ak + 1][ar] = 0.f;
            Bs[ak + 2][ar] = 0.f; Bs[ak + 3][ar] = 0.f;
        }
        __syncthreads();
#pragma unroll
        for (int k = 0; k < 16; ++k) {
            float a0 = As[k][ty * 4 + 0], a1 = As[k][ty * 4 + 1];
            float a2 = As[k][ty * 4 + 2], a3 = As[k][ty * 4 + 3];
            float b0 = Bs[k][tx * 4 + 0], b1 = Bs[k][tx * 4 + 1];
            float b2 = Bs[k][tx * 4 + 2], b3 = Bs[k][tx * 4 + 3];
            acc[0][0] += a0 * b0; acc[0][1] += a0 * b1; acc[0][2] += a0 * b2; acc[0][3] += a0 * b3;
            acc[1][0] += a1 * b0; acc[1][1] += a1 * b1; acc[1][2] += a1 * b2; acc[1][3] += a1 * b3;
            acc[2][0] += a2 * b0; acc[2][1] += a2 * b1; acc[2][2] += a2 * b2; acc[2][3] += a2 * b3;
            acc[3][0] += a3 * b0; acc[3][1] += a3 * b1; acc[3][2] += a3 * b2; acc[3][3] += a3 * b3;
        }
        __syncthreads();
    }
#pragma unroll
    for (int i = 0; i < 4; ++i) {
        int r = row0 + ty * 4 + i;
#pragma unroll
        for (int j = 0; j < 4; ++j) {
            int c = col0 + tx * 4 + j;
            if (c < N) C[(size_t)r * N + c] = acc[i][j];
        }
    }
}

// ---------------- RK4 stage combine ----------------
// stage 0: acc=k;      tmp=h+dt/2*k
// stage 1: acc+=2k;    tmp=h+dt/2*k
// stage 2: acc+=2k;    tmp=h+dt*k
// stage 3: h+=dt/6*(acc+k)
__global__ __launch_bounds__(256) void rk4_stage(float* __restrict__ h,
                                                 const float* __restrict__ k,
                                                 float* __restrict__ acc,
                                                 float* __restrict__ tmp,
                                                 float dt, int stage) {
    int i = blockIdx.x * blockDim.x + threadIdx.x;
    float4 kv = ((const float4*)k)[i];
    float4 hv = ((const float4*)h)[i];
    if (stage == 0) {
        ((float4*)acc)[i] = kv;
        float c = 0.5f * dt;
        float4 t = {hv.x + c * kv.x, hv.y + c * kv.y, hv.z + c * kv.z, hv.w + c * kv.w};
        ((float4*)tmp)[i] = t;
    } else if (stage == 1 || stage == 2) {
        float4 av = ((const float4*)acc)[i];
        av.x += 2.f * kv.x; av.y += 2.f * kv.y; av.z += 2.f * kv.z; av.w += 2.f * kv.w;
        ((float4*)acc)[i] = av;
        float c = (stage == 1) ? 0.5f * dt : dt;
        float4 t = {hv.x + c * kv.x, hv.y + c * kv.y, hv.z + c * kv.z, hv.w + c * kv.w};
        ((float4*)tmp)[i] = t;
    } else {
        float4 av = ((const float4*)acc)[i];
        float c = dt * (1.0f / 6.0f);
        hv.x += c * (av.x + kv.x); hv.y += c * (av.y + kv.y);
        hv.z += c * (av.z + kv.z); hv.w += c * (av.w + kv.w);
        ((float4*)h)[i] = hv;
    }
}

extern "C" void kernel_launch(void* const* d_in, const int* in_sizes, int n_in,
                              void* d_out, int out_size, void* d_ws, size_t ws_size,
                              hipStream_t stream) {
    const int*   tokens = (const int*)d_in[0];
    const float* embed  = (const float*)d_in[1];
    const float* ln1_g  = (const float*)d_in[2];
    const float* ln1_b  = (const float*)d_in[3];
    const float* w1     = (const float*)d_in[4];
    const float* b1     = (const float*)d_in[5];
    const float* w2     = (const float*)d_in[6];
    const float* b2     = (const float*)d_in[7];
    const float* nf_g   = (const float*)d_in[8];
    const float* nf_b   = (const float*)d_in[9];
    float* out = (float*)d_out;

    float* ws = (float*)d_ws;
    const size_t NH = (size_t)T_TOK * HIDDEN;   // 1M floats
    float* h    = ws;
    float* tmp  = ws + NH;
    float* acc  = ws + 2 * NH;
    float* kbuf = ws + 3 * NH;
    float* yln  = ws + 4 * NH;
    // z is T_TOK x FFDIM f32 (16 MB). Prefer ws; fall back to d_out scratch
    // (d_out is 412 MB f32; z is dead before the head GEMM writes).
    float* z;
    if (ws_size >= (5 * NH + (size_t)T_TOK * FFDIM) * sizeof(float))
        z = ws + 5 * NH;
    else
        z = (float*)d_out;

    gather_rows<<<T_TOK, 256, 0, stream>>>(tokens, embed, h);

    // Graded RK4 step schedule. The flow f(h)=GELU(LN(h)w1)w2 has effective
    // Lipschitz ~1/sigma(h); sigma(h0)~0.02 grows to ~0.4 by t=1, so uniform
    // dt=1/16 is wildly inaccurate in the initial transient (L*dt ~ 3).
    // Keep L*dt <= ~0.3 everywhere: small steps first, growing later.
    // Sums exactly to 1.0.
    const int NSCHED = 34;
    float steps[NSCHED];
    {
        int i = 0;
        for (int j = 0; j < 8; ++j) steps[i++] = 1.0f / 256.0f;   // -> 1/32
        for (int j = 0; j < 8; ++j) steps[i++] = 1.0f / 64.0f;    // -> 5/32
        for (int j = 0; j < 8; ++j) steps[i++] = 1.0f / 32.0f;    // -> 13/32
        for (int j = 0; j < 10; ++j) steps[i++] = 0.059375f;      // -> 1.0
    }

    const int n4blocks = (T_TOK * HIDDEN / 4) / 256;  // 1024
    for (int step = 0; step < NSCHED; ++step) {
        const float dt = steps[step];
        for (int stage = 0; stage < 4; ++stage) {
            const float* src = (stage == 0) ? h : tmp;
            ln_rows<<<T_TOK, 256, 0, stream>>>(src, ln1_g, ln1_b, yln);
            gemm_rrr<1, 1><<<dim3(FFDIM / 64, T_TOK / 64), 256, 0, stream>>>(
                yln, w1, b1, z, T_TOK, FFDIM, HIDDEN);
            gemm_rrr<0, 1><<<dim3(HIDDEN / 64, T_TOK / 64), 256, 0, stream>>>(
                z, w2, b2, kbuf, T_TOK, HIDDEN, FFDIM);
            rk4_stage<<<n4blocks, 256, 0, stream>>>(h, kbuf, acc, tmp, dt, stage);
        }
    }

    ln_rows<<<T_TOK, 256, 0, stream>>>(h, nf_g, nf_b, yln);
    gemm_head<<<dim3((VOCAB + 63) / 64, T_TOK / 64), 256, 0, stream>>>(
        yln, embed, out, T_TOK, VOCAB, HIDDEN);
}